// Round 1
// baseline (28.982 us; speedup 1.0000x reference)
//
#include <hip/hip_runtime.h>

// TabEncoder segment-mean: out[b, seg-1, :] = mean over {s : mask[b,s]//100 == seg} of x[b, s, :]
// B=32, S=2048, D=512, segments 1..64 emitted (segment 0 dropped).
//
// One block per (b, seg): deterministic ballot-compaction of matching row
// indices, then coalesced float4 gather-accumulate. No atomics, no workspace.

constexpr int S = 2048;
constexpr int D = 512;
constexpr int NSEG_OUT = 64;

__global__ __launch_bounds__(256, 8) void seg_mean_kernel(
    const float* __restrict__ src,   // [B, S, D] f32
    const int* __restrict__ mask,    // [B, S] int32
    float* __restrict__ dst) {       // [B, 64, D] f32
  const int segm1 = blockIdx.x;                     // 0..63 -> segment segm1+1
  const int b = blockIdx.y;                         // 0..31
  const int tid = threadIdx.x;                      // 0..255
  const unsigned char myseg = (unsigned char)(segm1 + 1);

  __shared__ unsigned char seg_lds[S];   // segment id per s
  __shared__ short list[S];              // compacted matching s indices
  __shared__ int mcount;
  __shared__ float combine[D];           // cross-half reduction buffer

  // Phase 1: load mask row, precompute segment ids into LDS (int4-vectorized).
  const int4* m4 = (const int4*)(mask + (size_t)b * S);
  #pragma unroll
  for (int it = 0; it < (S / 4) / 256; ++it) {     // 2 iterations
    const int i = it * 256 + tid;
    const int4 v = m4[i];
    seg_lds[i * 4 + 0] = (unsigned char)(v.x / 100);
    seg_lds[i * 4 + 1] = (unsigned char)(v.y / 100);
    seg_lds[i * 4 + 2] = (unsigned char)(v.z / 100);
    seg_lds[i * 4 + 3] = (unsigned char)(v.w / 100);
  }
  __syncthreads();

  // Phase 2: wave 0 compacts matching indices in ascending s order
  // (ballot + prefix-popcount -> deterministic order, no atomics).
  if (tid < 64) {
    int cnt = 0;
    for (int base = 0; base < S; base += 64) {
      const bool match = (seg_lds[base + tid] == myseg);
      const unsigned long long bal = __ballot(match);
      if (match) {
        const int pos = __popcll(bal & ((1ull << tid) - 1ull));
        list[cnt + pos] = (short)(base + tid);
      }
      cnt += __popcll(bal);
    }
    if (tid == 0) mcount = cnt;
  }
  __syncthreads();

  const int m = mcount;
  const int h = tid >> 7;        // half 0 sums rows 0,2,4,..., half 1 rows 1,3,5,...
  const int dt = tid & 127;      // float4 lane within the 512-wide row

  const float4* row4 = (const float4*)(src + (size_t)b * S * D);
  float4 acc = make_float4(0.f, 0.f, 0.f, 0.f);

  // Phase 3: gather-accumulate matched rows (each row = contiguous 2 KB,
  // perfectly coalesced). 2x unrolled for 2 outstanding loads per wave.
  int i = h;
  for (; i + 2 < m; i += 4) {
    const int s0 = list[i];
    const int s1 = list[i + 2];
    const float4 v0 = row4[(size_t)s0 * (D / 4) + dt];
    const float4 v1 = row4[(size_t)s1 * (D / 4) + dt];
    acc.x += v0.x; acc.y += v0.y; acc.z += v0.z; acc.w += v0.w;
    acc.x += v1.x; acc.y += v1.y; acc.z += v1.z; acc.w += v1.w;
  }
  if (i < m) {
    const int s0 = list[i];
    const float4 v0 = row4[(size_t)s0 * (D / 4) + dt];
    acc.x += v0.x; acc.y += v0.y; acc.z += v0.z; acc.w += v0.w;
  }

  // Phase 4: combine halves in fixed order, scale by 1/max(count,1), store.
  if (h == 1) {
    ((float4*)combine)[dt] = acc;
  }
  __syncthreads();
  if (h == 0) {
    const float4 o = ((float4*)combine)[dt];
    const float inv = 1.0f / fmaxf((float)m, 1.0f);
    float4 r;
    r.x = (acc.x + o.x) * inv;
    r.y = (acc.y + o.y) * inv;
    r.z = (acc.z + o.z) * inv;
    r.w = (acc.w + o.w) * inv;
    float4* out4 = (float4*)(dst + ((size_t)b * NSEG_OUT + segm1) * D);
    out4[dt] = r;
  }
}

extern "C" void kernel_launch(void* const* d_in, const int* in_sizes, int n_in,
                              void* d_out, int out_size, void* d_ws, size_t ws_size,
                              hipStream_t stream) {
  const float* src = (const float*)d_in[0];   // [32, 2048, 512] f32
  const int* mask = (const int*)d_in[1];      // [32, 2048] int32
  float* dst = (float*)d_out;                 // [32, 64, 512] f32

  dim3 grid(NSEG_OUT, 32);   // (segment-1, batch)
  seg_mean_kernel<<<grid, 256, 0, stream>>>(src, mask, dst);
}

// Round 2
// 27.610 us; speedup vs baseline: 1.0497x; 1.0497x over previous
//
#include <hip/hip_runtime.h>

// TabEncoder segment-mean: out[b, seg-1, :] = mean over {s : mask[b,s]//100 == seg} of x[b, s, :]
// B=32, S=2048, D=512, segments 1..64 emitted (segment 0 dropped).
//
// One block per (b, seg), 4 waves; each wave independently compacts + gathers
// its own s-quarter (no barriers before the gather), single final combine.

constexpr int S = 2048;
constexpr int D = 512;
constexpr int D4 = D / 4;        // 128 float4 per row
constexpr int NSEG_OUT = 64;

__global__ __launch_bounds__(256, 8) void seg_mean_kernel(
    const float* __restrict__ src,   // [B, S, D] f32
    const int* __restrict__ mask,    // [B, S] int32
    float* __restrict__ dst) {       // [B, 64, D] f32
  const int segm1 = blockIdx.x;                  // 0..63 -> segment segm1+1
  const int b = blockIdx.y;                      // 0..31
  const int tid = threadIdx.x;                   // 0..255
  const int w = tid >> 6;                        // wave 0..3, owns s in [512w, 512w+512)
  const int lane = tid & 63;
  const int myseg = segm1 + 1;

  __shared__ float sums[4][D];                   // per-wave partial row sums
  __shared__ short list[4][512];                 // per-wave matched s (worst-case safe)
  __shared__ int wcnt[4];

  // --- Per-wave mask read: 2 x int4 per lane covers the wave's 512 s values.
  // Element j of the int4 at lane L maps to s = 512w + 256q + 4L + j.
  const int4* m4 = (const int4*)(mask + (size_t)b * S) + (size_t)w * 128;
  const int4 q0 = m4[lane];
  const int4 q1 = m4[64 + lane];

  unsigned long long bal[8];
  bal[0] = __ballot(q0.x / 100 == myseg);
  bal[1] = __ballot(q0.y / 100 == myseg);
  bal[2] = __ballot(q0.z / 100 == myseg);
  bal[3] = __ballot(q0.w / 100 == myseg);
  bal[4] = __ballot(q1.x / 100 == myseg);
  bal[5] = __ballot(q1.y / 100 == myseg);
  bal[6] = __ballot(q1.z / 100 == myseg);
  bal[7] = __ballot(q1.w / 100 == myseg);

  // --- Wave-uniform extraction into the per-wave LDS list (deterministic order).
  int cnt = 0;
  #pragma unroll
  for (int r = 0; r < 8; ++r) {
    unsigned long long bb = bal[r];
    const int sb = 512 * w + 256 * (r >> 2) + (r & 3);
    while (bb) {
      const int L = __ffsll((long long)bb) - 1;
      bb &= bb - 1;
      if (lane == 0) list[w][cnt] = (short)(sb + 4 * L);
      ++cnt;                                     // uniform across the wave
    }
  }
  if (lane == 0) wcnt[w] = cnt;

  // --- Gather-accumulate full rows: lane covers float4 slots {lane, lane+64}.
  const float4* row4 = (const float4*)(src + (size_t)b * S * D);
  float4 a0 = make_float4(0.f, 0.f, 0.f, 0.f);
  float4 a1 = make_float4(0.f, 0.f, 0.f, 0.f);

  int i = 0;
  for (; i + 1 < cnt; i += 2) {                  // 2 rows (4 KB) in flight per wave
    const int s0 = list[w][i];
    const int s1 = list[w][i + 1];
    const float4* r0 = row4 + (size_t)s0 * D4;
    const float4* r1 = row4 + (size_t)s1 * D4;
    const float4 v00 = r0[lane];
    const float4 v01 = r0[64 + lane];
    const float4 v10 = r1[lane];
    const float4 v11 = r1[64 + lane];
    a0.x += v00.x; a0.y += v00.y; a0.z += v00.z; a0.w += v00.w;
    a1.x += v01.x; a1.y += v01.y; a1.z += v01.z; a1.w += v01.w;
    a0.x += v10.x; a0.y += v10.y; a0.z += v10.z; a0.w += v10.w;
    a1.x += v11.x; a1.y += v11.y; a1.z += v11.z; a1.w += v11.w;
  }
  if (i < cnt) {
    const int s0 = list[w][i];
    const float4* r0 = row4 + (size_t)s0 * D4;
    const float4 v00 = r0[lane];
    const float4 v01 = r0[64 + lane];
    a0.x += v00.x; a0.y += v00.y; a0.z += v00.z; a0.w += v00.w;
    a1.x += v01.x; a1.y += v01.y; a1.z += v01.z; a1.w += v01.w;
  }

  ((float4*)sums[w])[lane] = a0;
  ((float4*)sums[w])[64 + lane] = a1;
  __syncthreads();

  // --- Final combine in fixed wave order, scale, coalesced store.
  if (tid < D4) {
    const int m = wcnt[0] + wcnt[1] + wcnt[2] + wcnt[3];
    const float inv = 1.0f / fmaxf((float)m, 1.0f);
    const float4 s0 = ((const float4*)sums[0])[tid];
    const float4 s1 = ((const float4*)sums[1])[tid];
    const float4 s2 = ((const float4*)sums[2])[tid];
    const float4 s3 = ((const float4*)sums[3])[tid];
    float4 r;
    r.x = (s0.x + s1.x + s2.x + s3.x) * inv;
    r.y = (s0.y + s1.y + s2.y + s3.y) * inv;
    r.z = (s0.z + s1.z + s2.z + s3.z) * inv;
    r.w = (s0.w + s1.w + s2.w + s3.w) * inv;
    float4* out4 = (float4*)(dst + ((size_t)b * NSEG_OUT + segm1) * D);
    out4[tid] = r;
  }
}

extern "C" void kernel_launch(void* const* d_in, const int* in_sizes, int n_in,
                              void* d_out, int out_size, void* d_ws, size_t ws_size,
                              hipStream_t stream) {
  const float* src = (const float*)d_in[0];   // [32, 2048, 512] f32
  const int* mask = (const int*)d_in[1];      // [32, 2048] int32
  float* dst = (float*)d_out;                 // [32, 64, 512] f32

  dim3 grid(NSEG_OUT, 32);   // (segment-1, batch)
  seg_mean_kernel<<<grid, 256, 0, stream>>>(src, mask, dst);
}

// Round 3
// 26.793 us; speedup vs baseline: 1.0817x; 1.0305x over previous
//
#include <hip/hip_runtime.h>

// TabEncoder segment-mean: out[b, seg-1, :] = mean over {s : mask[b,s]//100 == seg} of x[b, s, :]
// B=32, S=2048, D=512, segments 1..64 emitted (segment 0 dropped).
//
// One block per (b, seg), 4 waves. Lane-parallel ballot compaction into one
// block-shared flat list; each wave gathers a contiguous, balanced (+/-1 row)
// quarter of the list with an unroll-4 float4 loop. Deterministic order.

constexpr int S = 2048;
constexpr int D = 512;
constexpr int D4 = D / 4;        // 128 float4 per row
constexpr int NSEG_OUT = 64;

__global__ __launch_bounds__(256, 8) void seg_mean_kernel(
    const float* __restrict__ src,   // [B, S, D] f32
    const int* __restrict__ mask,    // [B, S] int32
    float* __restrict__ dst) {       // [B, 64, D] f32
  const int segm1 = blockIdx.x;                  // 0..63 -> segment segm1+1
  const int b = blockIdx.y;                      // 0..31
  const int tid = threadIdx.x;                   // 0..255
  const int w = tid >> 6;                        // wave 0..3, owns s in [512w, 512w+512)
  const int lane = tid & 63;
  const int myseg = segm1 + 1;

  __shared__ float sums[4][D];                   // per-wave partial row sums
  __shared__ short list[S];                      // flat matched-s list (worst-case safe)
  __shared__ int wcnt[4];

  // --- Per-wave mask read: 2 x int4 per lane covers the wave's 512 s values.
  // Ballot r (r = 4q + j), bit L  ->  s = 512w + 256q + 4L + j.
  const int4* m4 = (const int4*)(mask + (size_t)b * S) + (size_t)w * 128;
  const int4 q0 = m4[lane];
  const int4 q1 = m4[64 + lane];

  unsigned long long bal[8];
  bal[0] = __ballot(q0.x / 100 == myseg);
  bal[1] = __ballot(q0.y / 100 == myseg);
  bal[2] = __ballot(q0.z / 100 == myseg);
  bal[3] = __ballot(q0.w / 100 == myseg);
  bal[4] = __ballot(q1.x / 100 == myseg);
  bal[5] = __ballot(q1.y / 100 == myseg);
  bal[6] = __ballot(q1.z / 100 == myseg);
  bal[7] = __ballot(q1.w / 100 == myseg);

  int pre[8];
  int cnt = 0;
  #pragma unroll
  for (int r = 0; r < 8; ++r) { pre[r] = cnt; cnt += __popcll(bal[r]); }
  if (lane == 0) wcnt[w] = cnt;
  __syncthreads();                               // B1: all wave counts visible

  const int c0 = wcnt[0], c1 = wcnt[1], c2 = wcnt[2], c3 = wcnt[3];
  const int m = c0 + c1 + c2 + c3;
  int base = 0;
  if (w > 0) base += c0;
  if (w > 1) base += c1;
  if (w > 2) base += c2;

  // --- Lane-parallel extraction into the flat list (fixed (r, L) order).
  const unsigned long long mylow = (1ull << lane) - 1ull;
  #pragma unroll
  for (int r = 0; r < 8; ++r) {
    if ((bal[r] >> lane) & 1ull) {
      const int pos = pre[r] + __popcll(bal[r] & mylow);
      list[base + pos] = (short)(512 * w + 256 * (r >> 2) + 4 * lane + (r & 3));
    }
  }
  __syncthreads();                               // B2: full list visible

  // --- Balanced gather: wave w owns contiguous logical chunk [lo, hi).
  const int lo = (m * w) >> 2;
  const int hi = (m * (w + 1)) >> 2;
  const float4* row4 = (const float4*)(src + (size_t)b * S * D);
  float4 a0 = make_float4(0.f, 0.f, 0.f, 0.f);
  float4 a1 = make_float4(0.f, 0.f, 0.f, 0.f);

  int i = lo;
  for (; i + 3 < hi; i += 4) {                   // 4 rows (8 KB) in flight per wave
    const int s0 = list[i], s1 = list[i + 1], s2 = list[i + 2], s3 = list[i + 3];
    const float4* r0 = row4 + (size_t)s0 * D4;
    const float4* r1 = row4 + (size_t)s1 * D4;
    const float4* r2 = row4 + (size_t)s2 * D4;
    const float4* r3 = row4 + (size_t)s3 * D4;
    const float4 v00 = r0[lane],      v01 = r0[64 + lane];
    const float4 v10 = r1[lane],      v11 = r1[64 + lane];
    const float4 v20 = r2[lane],      v21 = r2[64 + lane];
    const float4 v30 = r3[lane],      v31 = r3[64 + lane];
    a0.x += v00.x; a0.y += v00.y; a0.z += v00.z; a0.w += v00.w;
    a1.x += v01.x; a1.y += v01.y; a1.z += v01.z; a1.w += v01.w;
    a0.x += v10.x; a0.y += v10.y; a0.z += v10.z; a0.w += v10.w;
    a1.x += v11.x; a1.y += v11.y; a1.z += v11.z; a1.w += v11.w;
    a0.x += v20.x; a0.y += v20.y; a0.z += v20.z; a0.w += v20.w;
    a1.x += v21.x; a1.y += v21.y; a1.z += v21.z; a1.w += v21.w;
    a0.x += v30.x; a0.y += v30.y; a0.z += v30.z; a0.w += v30.w;
    a1.x += v31.x; a1.y += v31.y; a1.z += v31.z; a1.w += v31.w;
  }
  for (; i < hi; ++i) {
    const int s0 = list[i];
    const float4* r0 = row4 + (size_t)s0 * D4;
    const float4 v00 = r0[lane], v01 = r0[64 + lane];
    a0.x += v00.x; a0.y += v00.y; a0.z += v00.z; a0.w += v00.w;
    a1.x += v01.x; a1.y += v01.y; a1.z += v01.z; a1.w += v01.w;
  }

  ((float4*)sums[w])[lane] = a0;
  ((float4*)sums[w])[64 + lane] = a1;
  __syncthreads();                               // B3: partials visible

  // --- Final combine in fixed wave order, scale, coalesced store.
  if (tid < D4) {
    const float inv = 1.0f / fmaxf((float)m, 1.0f);
    const float4 s0 = ((const float4*)sums[0])[tid];
    const float4 s1 = ((const float4*)sums[1])[tid];
    const float4 s2 = ((const float4*)sums[2])[tid];
    const float4 s3 = ((const float4*)sums[3])[tid];
    float4 r;
    r.x = (s0.x + s1.x + s2.x + s3.x) * inv;
    r.y = (s0.y + s1.y + s2.y + s3.y) * inv;
    r.z = (s0.z + s1.z + s2.z + s3.z) * inv;
    r.w = (s0.w + s1.w + s2.w + s3.w) * inv;
    float4* out4 = (float4*)(dst + ((size_t)b * NSEG_OUT + segm1) * D);
    out4[tid] = r;
  }
}

extern "C" void kernel_launch(void* const* d_in, const int* in_sizes, int n_in,
                              void* d_out, int out_size, void* d_ws, size_t ws_size,
                              hipStream_t stream) {
  const float* src = (const float*)d_in[0];   // [32, 2048, 512] f32
  const int* mask = (const int*)d_in[1];      // [32, 2048] int32
  float* dst = (float*)d_out;                 // [32, 64, 512] f32

  dim3 grid(NSEG_OUT, 32);   // (segment-1, batch)
  seg_mean_kernel<<<grid, 256, 0, stream>>>(src, mask, dst);
}

// Round 4
// 26.749 us; speedup vs baseline: 1.0835x; 1.0017x over previous
//
#include <hip/hip_runtime.h>

// TabEncoder segment-mean: out[b, seg-1, :] = mean over {s : mask[b,s]//100 == seg} of x[b, s, :]
// B=32, S=2048, D=512, segments 1..64 emitted (segment 0 dropped).
//
// Grid (64, 32, 2): one block per (seg, b, D-half). 2x oversubscription vs
// residency (16 blocks/CU) lets the HW dispatcher backfill CUs that finish
// early, shrinking the random-workload tail. Each block: lane-parallel ballot
// compaction of matching rows, then balanced per-wave gather of its 256-col
// half (1 KB coalesced per row). No atomics; deterministic order.

constexpr int S = 2048;
constexpr int D = 512;
constexpr int D4 = D / 4;        // 128 float4 per full row
constexpr int DH = 256;          // columns per block (D/2)
constexpr int DH4 = DH / 4;      // 64 float4 per half row
constexpr int NSEG_OUT = 64;

__global__ __launch_bounds__(256, 8) void seg_mean_kernel(
    const float* __restrict__ src,   // [B, S, D] f32
    const int* __restrict__ mask,    // [B, S] int32
    float* __restrict__ dst) {       // [B, 64, D] f32
  const int segm1 = blockIdx.x;                  // 0..63 -> segment segm1+1
  const int b = blockIdx.y;                      // 0..31
  const int z = blockIdx.z;                      // 0..1 column half
  const int tid = threadIdx.x;                   // 0..255
  const int w = tid >> 6;                        // wave 0..3, owns s in [512w, 512w+512)
  const int lane = tid & 63;
  const int myseg = segm1 + 1;

  __shared__ float sums[4][DH];                  // per-wave partial half-row sums
  __shared__ short list[S];                      // flat matched-s list (worst-case safe)
  __shared__ int wcnt[4];

  // --- Per-wave mask read: 2 x int4 per lane covers the wave's 512 s values.
  // Ballot r (r = 4q + j), bit L  ->  s = 512w + 256q + 4L + j.
  const int4* m4 = (const int4*)(mask + (size_t)b * S) + (size_t)w * 128;
  const int4 q0 = m4[lane];
  const int4 q1 = m4[64 + lane];

  unsigned long long bal[8];
  bal[0] = __ballot(q0.x / 100 == myseg);
  bal[1] = __ballot(q0.y / 100 == myseg);
  bal[2] = __ballot(q0.z / 100 == myseg);
  bal[3] = __ballot(q0.w / 100 == myseg);
  bal[4] = __ballot(q1.x / 100 == myseg);
  bal[5] = __ballot(q1.y / 100 == myseg);
  bal[6] = __ballot(q1.z / 100 == myseg);
  bal[7] = __ballot(q1.w / 100 == myseg);

  int pre[8];
  int cnt = 0;
  #pragma unroll
  for (int r = 0; r < 8; ++r) { pre[r] = cnt; cnt += __popcll(bal[r]); }
  if (lane == 0) wcnt[w] = cnt;
  __syncthreads();                               // B1: all wave counts visible

  const int c0 = wcnt[0], c1 = wcnt[1], c2 = wcnt[2], c3 = wcnt[3];
  const int m = c0 + c1 + c2 + c3;
  int base = 0;
  if (w > 0) base += c0;
  if (w > 1) base += c1;
  if (w > 2) base += c2;

  // --- Lane-parallel extraction into the flat list (fixed (r, L) order).
  const unsigned long long mylow = (1ull << lane) - 1ull;
  #pragma unroll
  for (int r = 0; r < 8; ++r) {
    if ((bal[r] >> lane) & 1ull) {
      const int pos = pre[r] + __popcll(bal[r] & mylow);
      list[base + pos] = (short)(512 * w + 256 * (r >> 2) + 4 * lane + (r & 3));
    }
  }
  __syncthreads();                               // B2: full list visible

  // --- Balanced gather of this block's column half: wave w owns [lo, hi).
  // One 1 KB coalesced load per row per wave (64 lanes x float4).
  const int lo = (m * w) >> 2;
  const int hi = (m * (w + 1)) >> 2;
  const float4* half4 = (const float4*)(src + (size_t)b * S * D) + (size_t)z * DH4;
  float4 a0 = make_float4(0.f, 0.f, 0.f, 0.f);

  int i = lo;
  for (; i + 3 < hi; i += 4) {                   // 4 rows (4 KB) in flight per wave
    const int s0 = list[i], s1 = list[i + 1], s2 = list[i + 2], s3 = list[i + 3];
    const float4 v0 = half4[(size_t)s0 * D4 + lane];
    const float4 v1 = half4[(size_t)s1 * D4 + lane];
    const float4 v2 = half4[(size_t)s2 * D4 + lane];
    const float4 v3 = half4[(size_t)s3 * D4 + lane];
    a0.x += v0.x; a0.y += v0.y; a0.z += v0.z; a0.w += v0.w;
    a0.x += v1.x; a0.y += v1.y; a0.z += v1.z; a0.w += v1.w;
    a0.x += v2.x; a0.y += v2.y; a0.z += v2.z; a0.w += v2.w;
    a0.x += v3.x; a0.y += v3.y; a0.z += v3.z; a0.w += v3.w;
  }
  for (; i < hi; ++i) {
    const float4 v0 = half4[(size_t)list[i] * D4 + lane];
    a0.x += v0.x; a0.y += v0.y; a0.z += v0.z; a0.w += v0.w;
  }

  ((float4*)sums[w])[lane] = a0;
  __syncthreads();                               // B3: partials visible

  // --- Final combine in fixed wave order, scale, coalesced store (64 float4).
  if (tid < DH4) {
    const float inv = 1.0f / fmaxf((float)m, 1.0f);
    const float4 s0 = ((const float4*)sums[0])[tid];
    const float4 s1 = ((const float4*)sums[1])[tid];
    const float4 s2 = ((const float4*)sums[2])[tid];
    const float4 s3 = ((const float4*)sums[3])[tid];
    float4 r;
    r.x = (s0.x + s1.x + s2.x + s3.x) * inv;
    r.y = (s0.y + s1.y + s2.y + s3.y) * inv;
    r.z = (s0.z + s1.z + s2.z + s3.z) * inv;
    r.w = (s0.w + s1.w + s2.w + s3.w) * inv;
    float4* out4 = (float4*)(dst + ((size_t)b * NSEG_OUT + segm1) * D + (size_t)z * DH);
    out4[tid] = r;
  }
}

extern "C" void kernel_launch(void* const* d_in, const int* in_sizes, int n_in,
                              void* d_out, int out_size, void* d_ws, size_t ws_size,
                              hipStream_t stream) {
  const float* src = (const float*)d_in[0];   // [32, 2048, 512] f32
  const int* mask = (const int*)d_in[1];      // [32, 2048] int32
  float* dst = (float*)d_out;                 // [32, 64, 512] f32

  dim3 grid(NSEG_OUT, 32, 2);   // (segment-1, batch, D-half)
  seg_mean_kernel<<<grid, 256, 0, stream>>>(src, mask, dst);
}